// Round 1
// baseline (322.163 us; speedup 1.0000x reference)
//
#include <hip/hip_runtime.h>

// Problem constants (match reference)
#define BATCH    64
#define HEIGHT   512
#define WIDTH    512
#define CHAN     3
#define PATCH    8
#define NPH      64
#define NPW      64
#define NP_TOT   4096          // NPH*NPW
#define NUM_MASK 3072          // 0.75 * NP_TOT

#define PER_IMG4 (HEIGHT * WIDTH * CHAN / 4)   // 196608 float4 per image
#define PER_ROW4 (WIDTH * CHAN / 4)            // 384 float4 per row
#define TOTAL4   (BATCH * PER_IMG4)            // 12,582,912 float4 total

// Kernel 1: initialize byte mask (64*4096 bytes) to 1, written as dwords.
__global__ void rm_init_mask(unsigned int* __restrict__ mask32) {
    int i = blockIdx.x * blockDim.x + threadIdx.x;
    if (i < BATCH * NP_TOT / 4) mask32[i] = 0x01010101u;
}

// Kernel 2: scatter zeros at masked patch indices.
// Indices within an image are a permutation prefix (distinct), so plain
// byte stores are race-free.
__global__ void rm_scatter_zeros(const int* __restrict__ mask_indices,
                                 unsigned char* __restrict__ mask) {
    int i = blockIdx.x * blockDim.x + threadIdx.x;
    if (i < BATCH * NUM_MASK) {
        int b = i / NUM_MASK;
        int idx = mask_indices[i];
        mask[b * NP_TOT + idx] = (unsigned char)0;
    }
}

// Kernel 3: out = in * mask, one float4 per thread.
// A patch covers 24 contiguous floats per row (8 px * 3 ch); 24 % 4 == 0,
// so each aligned float4 lies entirely within one patch -> one byte-mask
// lookup per 16B of data. Mask (256 KB) stays cache-resident.
__global__ void rm_apply_mask(const float4* __restrict__ in,
                              float4* __restrict__ out,
                              const unsigned char* __restrict__ mask) {
    int tid = blockIdx.x * blockDim.x + threadIdx.x;
    int b  = tid / PER_IMG4;
    int r  = tid - b * PER_IMG4;
    int y  = r / PER_ROW4;
    int x4 = r - y * PER_ROW4;
    int px = x4 / 6;          // 6 float4 per patch along x
    int py = y >> 3;          // PATCH = 8 rows per patch
    unsigned char m = mask[b * NP_TOT + (py << 6) + px];
    float4 v = in[tid];
    if (!m) { v.x = 0.f; v.y = 0.f; v.z = 0.f; v.w = 0.f; }
    out[tid] = v;
}

extern "C" void kernel_launch(void* const* d_in, const int* in_sizes, int n_in,
                              void* d_out, int out_size, void* d_ws, size_t ws_size,
                              hipStream_t stream) {
    const float* images       = (const float*)d_in[0];
    const int*   mask_indices = (const int*)d_in[1];
    float*       out          = (float*)d_out;
    unsigned char* mask       = (unsigned char*)d_ws;   // 256 KB used

    // 1) mask := 1  (65536 dwords)
    rm_init_mask<<<(BATCH * NP_TOT / 4 + 255) / 256, 256, 0, stream>>>(
        (unsigned int*)d_ws);

    // 2) mask[b, idx] := 0
    rm_scatter_zeros<<<(BATCH * NUM_MASK + 255) / 256, 256, 0, stream>>>(
        mask_indices, mask);

    // 3) out = in * mask   (TOTAL4 is an exact multiple of 256)
    rm_apply_mask<<<TOTAL4 / 256, 256, 0, stream>>>(
        (const float4*)images, (float4*)out, mask);
}

// Round 2
// 317.759 us; speedup vs baseline: 1.0139x; 1.0139x over previous
//
#include <hip/hip_runtime.h>

// Problem constants (match reference)
#define BATCH    64
#define HEIGHT   512
#define WIDTH    512
#define CHAN     3
#define PATCH    8
#define NPH      64
#define NPW      64
#define NP_TOT   4096          // NPH*NPW
#define NUM_MASK 3072          // 0.75 * NP_TOT

#define PER_IMG4 (HEIGHT * WIDTH * CHAN / 4)   // 196608 float4 per image
#define PER_ROW4 (WIDTH * CHAN / 4)            // 384 float4 per row
#define TOTAL4   (BATCH * PER_IMG4)            // 12,582,912 float4 total

// Kernel 1: initialize byte mask (64*4096 bytes) to 1, written as dwords.
// (d_ws is re-poisoned to 0xAA before every launch, so this must run each call.)
__global__ void rm_init_mask(unsigned int* __restrict__ mask32) {
    int i = blockIdx.x * blockDim.x + threadIdx.x;
    if (i < BATCH * NP_TOT / 4) mask32[i] = 0x01010101u;
}

// Kernel 2: scatter zeros at masked patch indices.
// Indices within an image are a permutation prefix (distinct) -> race-free.
__global__ void rm_scatter_zeros(const int* __restrict__ mask_indices,
                                 unsigned char* __restrict__ mask) {
    int i = blockIdx.x * blockDim.x + threadIdx.x;
    if (i < BATCH * NUM_MASK) {
        int b = i / NUM_MASK;
        int idx = mask_indices[i];
        mask[b * NP_TOT + idx] = (unsigned char)0;
    }
}

// Kernel 3: out = in * mask, one float4 per thread.
// 75% of patches are masked -> those lanes write zeros WITHOUT reading the
// input. The exec-masked global_load_dwordx4 only fetches active lanes'
// cache lines, cutting FETCH from 192 MiB to ~25% (+line-straddle overfetch).
// A patch covers 24 contiguous floats per row (6 float4), so each aligned
// float4 lies entirely within one patch -> one byte-mask lookup per 16 B.
__global__ void rm_apply_mask(const float4* __restrict__ in,
                              float4* __restrict__ out,
                              const unsigned char* __restrict__ mask) {
    int tid = blockIdx.x * blockDim.x + threadIdx.x;
    int b  = tid / PER_IMG4;
    int r  = tid - b * PER_IMG4;
    int y  = r / PER_ROW4;
    int x4 = r - y * PER_ROW4;
    int px = x4 / 6;          // 6 float4 per patch along x
    int py = y >> 3;          // PATCH = 8 rows per patch
    unsigned char m = mask[b * NP_TOT + (py << 6) + px];
    float4 v = make_float4(0.f, 0.f, 0.f, 0.f);
    if (m) v = in[tid];       // conditional load: masked lanes fetch nothing
    out[tid] = v;
}

extern "C" void kernel_launch(void* const* d_in, const int* in_sizes, int n_in,
                              void* d_out, int out_size, void* d_ws, size_t ws_size,
                              hipStream_t stream) {
    const float* images       = (const float*)d_in[0];
    const int*   mask_indices = (const int*)d_in[1];
    float*       out          = (float*)d_out;
    unsigned char* mask       = (unsigned char*)d_ws;   // 256 KB used

    // 1) mask := 1  (65536 dwords)
    rm_init_mask<<<(BATCH * NP_TOT / 4 + 255) / 256, 256, 0, stream>>>(
        (unsigned int*)d_ws);

    // 2) mask[b, idx] := 0
    rm_scatter_zeros<<<(BATCH * NUM_MASK + 255) / 256, 256, 0, stream>>>(
        mask_indices, mask);

    // 3) out = in * mask   (TOTAL4 is an exact multiple of 256)
    rm_apply_mask<<<TOTAL4 / 256, 256, 0, stream>>>(
        (const float4*)images, (float4*)out, mask);
}